// Round 13
// baseline (344.853 us; speedup 1.0000x reference)
//
#include <hip/hip_runtime.h>

#define NEG_SLOPE 0.2f

typedef __attribute__((ext_vector_type(8))) short bf16x8;
typedef __attribute__((ext_vector_type(4))) float f32x4;

__device__ inline unsigned short f2bf(float f) {
    unsigned int u = __float_as_uint(f);
    unsigned int r = (u + 0x7fffu + ((u >> 16) & 1u)) >> 16;
    return (unsigned short)r;
}

__device__ inline bf16x8 pack8(float4 a, float4 b) {
    union { bf16x8 v; unsigned short u[8]; } r;
    r.u[0] = f2bf(a.x); r.u[1] = f2bf(a.y); r.u[2] = f2bf(a.z); r.u[3] = f2bf(a.w);
    r.u[4] = f2bf(b.x); r.u[5] = f2bf(b.y); r.u[6] = f2bf(b.z); r.u[7] = f2bf(b.w);
    return r.v;
}

// ---------------- prep: W1/W2/W3 -> chunk-major bf16, zero cnt+gmax ----------------
__device__ inline void wprep_item(const float* __restrict__ W, unsigned short* __restrict__ Wl,
                                  int K, int NOUT, int item) {
    int kc = item / NOUT, nn = item % NOUT;
    unsigned int w[4];
#pragma unroll
    for (int p = 0; p < 4; p++) {
        unsigned int lo = f2bf(W[(size_t)(kc * 8 + 2 * p + 0) * NOUT + nn]);
        unsigned int hi = f2bf(W[(size_t)(kc * 8 + 2 * p + 1) * NOUT + nn]);
        w[p] = lo | (hi << 16);
    }
    uint4 o; o.x = w[0]; o.y = w[1]; o.z = w[2]; o.w = w[3];
    ((uint4*)Wl)[item] = o;
}

__global__ void prep_all_k(const float* __restrict__ W1, unsigned short* __restrict__ Wl1,
                           const float* __restrict__ W2, unsigned short* __restrict__ Wl2,
                           const float* __restrict__ W3, unsigned short* __restrict__ Wl3,
                           int* __restrict__ cnt, unsigned int* __restrict__ gmaxb,
                           int ncnt4) {
    int r = blockIdx.x * blockDim.x + threadIdx.x;
    if (r < 4096) { wprep_item(W1, Wl1, 128, 256, r); return; }
    r -= 4096;
    if (r < 4096) { wprep_item(W2, Wl2, 256, 128, r); return; }
    r -= 4096;
    if (r < 512)  { wprep_item(W3, Wl3, 128, 32, r); return; }
    r -= 512;
    if (r < ncnt4) { ((int4*)cnt)[r] = make_int4(0, 0, 0, 0); return; }
    r -= ncnt4;
    if (r == 0) { gmaxb[0] = 0u; gmaxb[1] = 0u; gmaxb[2] = 0u; gmaxb[3] = 0u; }
}

// ---------------- CSR build ----------------
__global__ void hist_k(const int* __restrict__ ei, int* __restrict__ cnt, int Eo, int Eext) {
    int e = blockIdx.x * blockDim.x + threadIdx.x;
    if (e >= Eext) return;
    int dv = (e < Eo) ? ei[Eo + e] : (e - Eo);
    atomicAdd(&cnt[dv], 1);
}

__global__ __launch_bounds__(256) void scan1_k(const int* __restrict__ cnt, int* __restrict__ rowptr,
                                               int* __restrict__ bsum, int n) {
    __shared__ int ts[256];
    int tid = threadIdx.x;
    int base = blockIdx.x * 1024 + tid * 4;
    int v0 = (base + 0 < n) ? cnt[base + 0] : 0;
    int v1 = (base + 1 < n) ? cnt[base + 1] : 0;
    int v2 = (base + 2 < n) ? cnt[base + 2] : 0;
    int v3 = (base + 3 < n) ? cnt[base + 3] : 0;
    int e1 = v0, e2 = e1 + v1, e3 = e2 + v2, tot = e3 + v3;
    ts[tid] = tot;
    __syncthreads();
    for (int off = 1; off < 256; off <<= 1) {
        int x = (tid >= off) ? ts[tid - off] : 0;
        __syncthreads();
        ts[tid] += x;
        __syncthreads();
    }
    int excl = ts[tid] - tot;
    if (base + 0 < n) rowptr[base + 0] = excl;
    if (base + 1 < n) rowptr[base + 1] = excl + e1;
    if (base + 2 < n) rowptr[base + 2] = excl + e2;
    if (base + 3 < n) rowptr[base + 3] = excl + e3;
    if (tid == 255) bsum[blockIdx.x] = ts[255];
}

// 64-lane shfl exclusive scan (nb <= 64)
__global__ void scan2_k(int* __restrict__ bsum, int nb) {
    int t = threadIdx.x;
    int orig = (t < nb) ? bsum[t] : 0;
    int v = orig;
    for (int off = 1; off < 64; off <<= 1) {
        int u = __shfl_up(v, off);
        if (t >= off) v += u;
    }
    if (t < nb) bsum[t] = v - orig;
}

__global__ void scan3_k(int* __restrict__ rowptr, int* __restrict__ cursors,
                        const int* __restrict__ bsum, int n) {
    int gid = blockIdx.x * blockDim.x + threadIdx.x;
    if (gid >= n) return;
    int v = rowptr[gid] + bsum[gid >> 10];
    rowptr[gid] = v;
    cursors[gid] = v;
}

__global__ void scatter_k(const int* __restrict__ ei, int* __restrict__ cursors,
                          int* __restrict__ csr_src, int Eo, int Eext) {
    int e = blockIdx.x * blockDim.x + threadIdx.x;
    if (e >= Eext) return;
    int sv, dv;
    if (e < Eo) { sv = ei[e]; dv = ei[Eo + e]; }
    else        { sv = dv = e - Eo; }
    int idx = atomicAdd(&cursors[dv], 1);
    csr_src[idx] = sv;
}

// 16-lane-per-node parallel rank-sort in LDS (deterministic multiset order)
__global__ __launch_bounds__(256) void sortw_k(const int* __restrict__ rowptr, const int* __restrict__ cnt,
                                               int* __restrict__ csr_src, int n) {
    __shared__ int buf[16][128];
    int grp = threadIdx.x >> 4;
    int sl  = threadIdx.x & 15;
    int node = blockIdx.x * 16 + grp;
    int ro = 0, deg = 0;
    if (node < n) { ro = rowptr[node]; deg = cnt[node]; }
    bool small = (deg <= 128);
    if (node < n && small) {
        for (int i = sl; i < deg; i += 16) buf[grp][i] = csr_src[ro + i];
    }
    __syncthreads();
    if (node < n) {
        if (small) {
            for (int i = sl; i < deg; i += 16) {
                int v = buf[grp][i];
                int r = 0;
                for (int j = 0; j < deg; j++) {
                    int u = buf[grp][j];
                    r += (u < v) || (u == v && j < i);
                }
                csr_src[ro + r] = v;
            }
        } else if (sl == 0) {
            for (int i = 1; i < deg; i++) {
                int key = csr_src[ro + i];
                int j = i - 1;
                while (j >= 0 && csr_src[ro + j] > key) { csr_src[ro + j + 1] = csr_src[ro + j]; j--; }
                csr_src[ro + j + 1] = key;
            }
        }
    }
}

// ---------------- MFMA GEMM (f32-or-bf16 in, bf16 out) + fused scores + fused gmax ----------------
template<int K, int NOUT, int Hh, bool AF32>
__global__ __launch_bounds__(256) void gemm_mfma(const void* __restrict__ Xin,
                                                 const unsigned short* __restrict__ Wl,
                                                 const float* __restrict__ As,
                                                 const float* __restrict__ Ad,
                                                 unsigned short* __restrict__ Hb,
                                                 float* __restrict__ esrc,
                                                 float* __restrict__ edst,
                                                 unsigned int* __restrict__ gmaxb, int M) {
    constexpr int NT    = NOUT / 16;
    constexpr int TP    = (NT < 8) ? NT : 8;
    constexpr int NPASS = NT / TP;
    constexpr int NCH   = K / 8;
    constexpr int HPP   = (TP * 16) / 32;

    __shared__ unsigned short wlds[K * NOUT];
    {
        const uint4* src = (const uint4*)Wl;
        uint4* dst = (uint4*)wlds;
        for (int i = threadIdx.x; i < K * NOUT / 8; i += 256) dst[i] = src[i];
    }
    __syncthreads();

    const int lane = threadIdx.x & 63;
    const int wid  = threadIdx.x >> 6;
    const int l15  = lane & 15;
    const int g4   = lane >> 4;
    const int m0   = blockIdx.x * 128 + wid * 32;
    const int m_s[2] = { m0 + l15, m0 + 16 + l15 };
    const int mi[2]  = { min(m_s[0], M - 1), min(m_s[1], M - 1) };

    const bf16x8* xb8 = (const bf16x8*)Xin;
    const float*  xf  = (const float*)Xin;
    const bf16x8* wl8 = (const bf16x8*)wlds;

    float gmx = 0.f;

    for (int pass = 0; pass < NPASS; ++pass) {
        f32x4 acc[TP][2];
#pragma unroll
        for (int tt = 0; tt < TP; ++tt)
#pragma unroll
            for (int s = 0; s < 2; ++s) acc[tt][s] = (f32x4)0.f;

        for (int ks = 0; ks < K / 32; ++ks) {
            int kc = ks * 4 + g4;
            bf16x8 a0, a1;
            if (AF32) {
                const float* r0 = xf + (size_t)mi[0] * K + kc * 8;
                const float* r1 = xf + (size_t)mi[1] * K + kc * 8;
                a0 = pack8(*(const float4*)r0, *(const float4*)(r0 + 4));
                a1 = pack8(*(const float4*)r1, *(const float4*)(r1 + 4));
            } else {
                a0 = xb8[(size_t)mi[0] * NCH + kc];
                a1 = xb8[(size_t)mi[1] * NCH + kc];
            }
#pragma unroll
            for (int tt = 0; tt < TP; ++tt) {
                int nn = (pass * TP + tt) * 16 + l15;
                bf16x8 b = wl8[kc * NOUT + nn];
                acc[tt][0] = __builtin_amdgcn_mfma_f32_16x16x32_bf16(b, a0, acc[tt][0], 0, 0, 0);
                acc[tt][1] = __builtin_amdgcn_mfma_f32_16x16x32_bf16(b, a1, acc[tt][1], 0, 0, 0);
            }
        }

        float s1[2][HPP], s2[2][HPP];
#pragma unroll
        for (int s = 0; s < 2; ++s)
#pragma unroll
            for (int hh = 0; hh < HPP; ++hh) { s1[s][hh] = 0.f; s2[s][hh] = 0.f; }

#pragma unroll
        for (int tt = 0; tt < TP; ++tt) {
            int t  = pass * TP + tt;
            int ch = t * 16 + g4 * 4;
            float4 asv = *(const float4*)(As + ch);
            float4 adv = *(const float4*)(Ad + ch);
            int hh = tt >> 1;
#pragma unroll
            for (int s = 0; s < 2; ++s) {
                f32x4 a = acc[tt][s];
                s1[s][hh] += a[0] * asv.x + a[1] * asv.y + a[2] * asv.z + a[3] * asv.w;
                s2[s][hh] += a[0] * adv.x + a[1] * adv.y + a[2] * adv.z + a[3] * adv.w;
                int m = m_s[s];
                if (m < M) {
                    ushort4 o;
                    o.x = f2bf(a[0]); o.y = f2bf(a[1]); o.z = f2bf(a[2]); o.w = f2bf(a[3]);
                    *(ushort4*)(Hb + (size_t)m * NOUT + ch) = o;
                }
            }
        }
#pragma unroll
        for (int s = 0; s < 2; ++s) {
            int m = m_s[s];
#pragma unroll
            for (int hh = 0; hh < HPP; ++hh) {
                float p1 = s1[s][hh], p2 = s2[s][hh];
                p1 += __shfl_xor(p1, 16); p1 += __shfl_xor(p1, 32);
                p2 += __shfl_xor(p2, 16); p2 += __shfl_xor(p2, 32);
                gmx = fmaxf(gmx, fabsf(p1));
                if (g4 == 0 && m < M) {
                    int h = pass * HPP + hh;
                    esrc[m * Hh + h] = p1;
                    edst[m * Hh + h] = p2;
                }
            }
        }
    }

    gmx = fmaxf(gmx, __shfl_xor(gmx, 1));
    gmx = fmaxf(gmx, __shfl_xor(gmx, 2));
    gmx = fmaxf(gmx, __shfl_xor(gmx, 4));
    gmx = fmaxf(gmx, __shfl_xor(gmx, 8));
    if (lane == 0) atomicMax(gmaxb, __float_as_uint(gmx));
}

// ---------------- fused softmax(ub) + gather-aggregate (quad-dedup exp) ----------------
__device__ inline void acc_bf8(float* acc, float a, uint4 p) {
    unsigned int u[4] = {p.x, p.y, p.z, p.w};
#pragma unroll
    for (int w = 0; w < 4; w++) {
        float lo = __uint_as_float(u[w] << 16);
        float hi = __uint_as_float(u[w] & 0xffff0000u);
        acc[2 * w + 0] += a * lo;
        acc[2 * w + 1] += a * hi;
    }
}

template<int HC, int Hh, bool PRED>
__global__ __launch_bounds__(256) void aggr_fused(const int* __restrict__ rowptr, const int* __restrict__ cnt,
                                                  const int* __restrict__ csr_src,
                                                  const float* __restrict__ esrc, const float* __restrict__ edst,
                                                  const unsigned int* __restrict__ gmaxb,
                                                  const unsigned short* __restrict__ Hb,
                                                  const float* __restrict__ bias,
                                                  unsigned short* __restrict__ OutB,
                                                  float* __restrict__ psrc, float* __restrict__ pdst,
                                                  const float* __restrict__ Wp, int n) {
    constexpr int TPN = HC / 8;
    constexpr int NPB = 256 / TPN;
    int node = blockIdx.x * NPB + threadIdx.x / TPN;
    if (node >= n) return;
    int t = threadIdx.x % TPN;
    int h = t >> 2;
    int sub = t & 3;
    int ro = rowptr[node], deg = cnt[node];
    float ed = edst[node * Hh + h];
    float g  = __uint_as_float(*gmaxb);
    float ub = g + ed; ub = (ub >= 0.f) ? ub : NEG_SLOPE * ub;   // >= max_j leaky(esrc[j]+ed)

    float s = 0.f;
    float acc[8];
#pragma unroll
    for (int c = 0; c < 8; c++) acc[c] = 0.f;

    int j = 0;
    for (; j + 4 <= deg; j += 4) {
        // XOR-permuted edge order per lane: payload addresses stay lane-local (no shfl in
        // the address chain - R7 lesson), only alpha values cross lanes.
        int t0 = csr_src[ro + j + sub];
        int t1 = csr_src[ro + j + (sub ^ 1)];
        int t2 = csr_src[ro + j + (sub ^ 2)];
        int t3 = csr_src[ro + j + (sub ^ 3)];
        float v = esrc[t0 * Hh + h] + ed;
        v = (v >= 0.f) ? v : NEG_SLOPE * v;
        float a0 = __expf(v - ub);          // alpha of edge j+sub (mine)
        float a1 = __shfl_xor(a0, 1);       // alpha of edge j+(sub^1)
        float a2 = __shfl_xor(a0, 2);       // alpha of edge j+(sub^2)
        float a3 = __shfl_xor(a1, 2);       // alpha of edge j+(sub^3)
        uint4 p0 = *(const uint4*)(Hb + (size_t)t0 * HC + 8 * t);
        uint4 p1 = *(const uint4*)(Hb + (size_t)t1 * HC + 8 * t);
        uint4 p2 = *(const uint4*)(Hb + (size_t)t2 * HC + 8 * t);
        uint4 p3 = *(const uint4*)(Hb + (size_t)t3 * HC + 8 * t);
        s += (a0 + a1) + (a2 + a3);
        acc_bf8(acc, a0, p0);
        acc_bf8(acc, a1, p1);
        acc_bf8(acc, a2, p2);
        acc_bf8(acc, a3, p3);
    }
    for (; j < deg; j++) {
        int s0 = csr_src[ro + j];
        float v0 = esrc[s0 * Hh + h] + ed;
        v0 = (v0 >= 0.f) ? v0 : NEG_SLOPE * v0;
        float a0 = __expf(v0 - ub);
        uint4 p0 = *(const uint4*)(Hb + (size_t)s0 * HC + 8 * t);
        s += a0;
        acc_bf8(acc, a0, p0);
    }

    float inv = 1.f / (s + 1e-16f);

    if (PRED) {
        float d1 = 0.f, d2 = 0.f;
#pragma unroll
        for (int c = 0; c < 8; c++) {
            float v = acc[c] * inv + bias[sub * 8 + c];
            v = v > 0.f ? v : 0.f;
            d1 += v * Wp[sub * 8 + c];
            d2 += v * Wp[32 + sub * 8 + c];
        }
        d1 += __shfl_xor(d1, 1); d1 += __shfl_xor(d1, 2);
        d2 += __shfl_xor(d2, 1); d2 += __shfl_xor(d2, 2);
        if (sub == 0) {
            psrc[node] = d1;
            pdst[node] = d2;
        }
    } else {
        uint4 o;
        unsigned int* op = (unsigned int*)&o;
#pragma unroll
        for (int w = 0; w < 4; w++) {
            float va = acc[2 * w + 0] * inv + bias[8 * t + 2 * w + 0];
            float vb = acc[2 * w + 1] * inv + bias[8 * t + 2 * w + 1];
            va = va > 0.f ? va : 0.f;
            vb = vb > 0.f ? vb : 0.f;
            op[w] = (unsigned int)f2bf(va) | ((unsigned int)f2bf(vb) << 16);
        }
        *(uint4*)(OutB + (size_t)node * HC + 8 * t) = o;
    }
}

// ---------------- rank-1 edge predictor ----------------
__global__ void predict2_k(const int* __restrict__ ei, const float* __restrict__ psrc,
                           const float* __restrict__ pdst, const float* __restrict__ bp,
                           float* __restrict__ out, int Eo) {
    int e = blockIdx.x * blockDim.x + threadIdx.x;
    if (e >= Eo) return;
    float acc = psrc[ei[e]] + pdst[ei[Eo + e]] + bp[0];
    float sg = 1.f / (1.f + __expf(-acc));
    out[e] = sg * 4.f + 1.f;
}

extern "C" void kernel_launch(void* const* d_in, const int* in_sizes, int n_in,
                              void* d_out, int out_size, void* d_ws, size_t ws_size,
                              hipStream_t stream) {
    const float* x   = (const float*)d_in[0];
    const int*   ei  = (const int*)  d_in[1];
    const float* W1  = (const float*)d_in[2];
    const float* as1 = (const float*)d_in[3];
    const float* ad1 = (const float*)d_in[4];
    const float* b1  = (const float*)d_in[5];
    const float* W2  = (const float*)d_in[6];
    const float* as2 = (const float*)d_in[7];
    const float* ad2 = (const float*)d_in[8];
    const float* b2  = (const float*)d_in[9];
    const float* W3  = (const float*)d_in[10];
    const float* as3 = (const float*)d_in[11];
    const float* ad3 = (const float*)d_in[12];
    const float* b3  = (const float*)d_in[13];
    const float* Wp  = (const float*)d_in[14];
    const float* bp  = (const float*)d_in[15];
    float* outp = (float*)d_out;

    const int n    = in_sizes[0] / 128;   // 50000
    const int Eo   = in_sizes[1] / 2;     // 800000
    const int Eext = Eo + n;              // 850000

    char* base = (char*)d_ws;
    unsigned short* hAb = (unsigned short*)base;   base += (size_t)n * 256 * 2;
    unsigned short* hBb = (unsigned short*)base;   base += (size_t)n * 256 * 2;
    unsigned short* Wl1 = (unsigned short*)base;   base += (size_t)128 * 256 * 2;
    unsigned short* Wl2 = (unsigned short*)base;   base += (size_t)256 * 128 * 2;
    unsigned short* Wl3 = (unsigned short*)base;   base += (size_t)128 * 32 * 2;
    float* esrc   = (float*)base;                  base += (size_t)n * 8 * 4;
    float* edst   = (float*)base;                  base += (size_t)n * 8 * 4;
    float* psrc   = (float*)base;                  base += (size_t)n * 4;
    float* pdst   = (float*)base;                  base += (size_t)n * 4;
    int* cnt      = (int*)base;                    base += (size_t)n * 4;
    unsigned int* gmaxb = (unsigned int*)base;     base += 16;
    int* rowptr   = (int*)base;                    base += (size_t)n * 4;
    int* cursors  = (int*)base;                    base += (size_t)n * 4;
    int* csr_src  = (int*)base;                    base += (size_t)Eext * 4;
    int* bsum     = (int*)base;

    const int TB = 256;
    auto nb = [](int tot, int tb) { return (tot + tb - 1) / tb; };

    // ---------------- prep (W conversions + zero cnt/gmax) ----------------
    int ncnt4 = n / 4;
    int prep_total = 4096 + 4096 + 512 + ncnt4 + 1;
    prep_all_k<<<nb(prep_total, TB), TB, 0, stream>>>(W1, Wl1, W2, Wl2, W3, Wl3,
                                                      cnt, gmaxb, ncnt4);

    // ---------------- CSR build (dst-sorted, value-sorted src) ----------------
    hist_k<<<nb(Eext, TB), TB, 0, stream>>>(ei, cnt, Eo, Eext);
    int nChunks = (n + 1023) / 1024;
    scan1_k<<<nChunks, 256, 0, stream>>>(cnt, rowptr, bsum, n);
    scan2_k<<<1, 64, 0, stream>>>(bsum, nChunks);
    scan3_k<<<nb(n, TB), TB, 0, stream>>>(rowptr, cursors, bsum, n);
    scatter_k<<<nb(Eext, TB), TB, 0, stream>>>(ei, cursors, csr_src, Eo, Eext);
    sortw_k<<<nb(n, 16), 256, 0, stream>>>(rowptr, cnt, csr_src, n);

    // ---------------- Layer 1: K=128, H=8, HC=256 (A read as f32, converted in-register) ----------------
    gemm_mfma<128, 256, 8, true><<<nb(n, 128), 256, 0, stream>>>(x, Wl1, as1, ad1, hAb, esrc, edst, gmaxb + 0, n);
    aggr_fused<256, 8, false><<<nb(n * 32, TB), TB, 0, stream>>>(rowptr, cnt, csr_src, esrc, edst, gmaxb + 0,
                                                                 hAb, b1, hBb, nullptr, nullptr, nullptr, n);

    // ---------------- Layer 2: K=256, H=4, HC=128 ----------------
    gemm_mfma<256, 128, 4, false><<<nb(n, 128), 256, 0, stream>>>(hBb, Wl2, as2, ad2, hAb, esrc, edst, gmaxb + 1, n);
    aggr_fused<128, 4, false><<<nb(n * 16, TB), TB, 0, stream>>>(rowptr, cnt, csr_src, esrc, edst, gmaxb + 1,
                                                                 hAb, b2, hBb, nullptr, nullptr, nullptr, n);

    // ---------------- Layer 3: K=128, H=1, HC=32 (fused rank-1 predictor dots) ----------------
    gemm_mfma<128, 32, 1, false><<<nb(n, 128), 256, 0, stream>>>(hBb, Wl3, as3, ad3, hAb, esrc, edst, gmaxb + 2, n);
    aggr_fused<32, 1, true><<<nb(n * 4, TB), TB, 0, stream>>>(rowptr, cnt, csr_src, esrc, edst, gmaxb + 2,
                                                              hAb, b3, nullptr, psrc, pdst, Wp, n);

    // ---------------- predictor ----------------
    predict2_k<<<nb(Eo, TB), TB, 0, stream>>>(ei, psrc, pdst, bp, outp, Eo);
}

// Round 14
// 331.149 us; speedup vs baseline: 1.0414x; 1.0414x over previous
//
#include <hip/hip_runtime.h>

#define NEG_SLOPE 0.2f

typedef __attribute__((ext_vector_type(8))) short bf16x8;
typedef __attribute__((ext_vector_type(4))) float f32x4;

__device__ inline unsigned short f2bf(float f) {
    unsigned int u = __float_as_uint(f);
    unsigned int r = (u + 0x7fffu + ((u >> 16) & 1u)) >> 16;
    return (unsigned short)r;
}

// ---------------- fused prep: x->bf16, W1/W2/W3 -> chunk-major bf16, zero cnt+gmax ----------------
__device__ inline void wprep_item(const float* __restrict__ W, unsigned short* __restrict__ Wl,
                                  int K, int NOUT, int item) {
    int kc = item / NOUT, nn = item % NOUT;
    unsigned int w[4];
#pragma unroll
    for (int p = 0; p < 4; p++) {
        unsigned int lo = f2bf(W[(size_t)(kc * 8 + 2 * p + 0) * NOUT + nn]);
        unsigned int hi = f2bf(W[(size_t)(kc * 8 + 2 * p + 1) * NOUT + nn]);
        w[p] = lo | (hi << 16);
    }
    uint4 o; o.x = w[0]; o.y = w[1]; o.z = w[2]; o.w = w[3];
    ((uint4*)Wl)[item] = o;
}

__global__ void prep_all_k(const float* __restrict__ x, unsigned short* __restrict__ Xb,
                           const float* __restrict__ W1, unsigned short* __restrict__ Wl1,
                           const float* __restrict__ W2, unsigned short* __restrict__ Wl2,
                           const float* __restrict__ W3, unsigned short* __restrict__ Wl3,
                           int* __restrict__ cnt, unsigned int* __restrict__ gmaxb,
                           int nx4, int ncnt4) {
    int gid = blockIdx.x * blockDim.x + threadIdx.x;
    if (gid < nx4) {
        float4 v = ((const float4*)x)[gid];
        ushort4 o;
        o.x = f2bf(v.x); o.y = f2bf(v.y); o.z = f2bf(v.z); o.w = f2bf(v.w);
        ((ushort4*)Xb)[gid] = o;
        return;
    }
    int r = gid - nx4;
    if (r < 4096) { wprep_item(W1, Wl1, 128, 256, r); return; }
    r -= 4096;
    if (r < 4096) { wprep_item(W2, Wl2, 256, 128, r); return; }
    r -= 4096;
    if (r < 512)  { wprep_item(W3, Wl3, 128, 32, r); return; }
    r -= 512;
    if (r < ncnt4) { ((int4*)cnt)[r] = make_int4(0, 0, 0, 0); return; }
    r -= ncnt4;
    if (r == 0) { gmaxb[0] = 0u; gmaxb[1] = 0u; gmaxb[2] = 0u; gmaxb[3] = 0u; }
}

// ---------------- CSR build ----------------
__global__ void hist_k(const int* __restrict__ ei, int* __restrict__ cnt, int Eo, int Eext) {
    int e = blockIdx.x * blockDim.x + threadIdx.x;
    if (e >= Eext) return;
    int dv = (e < Eo) ? ei[Eo + e] : (e - Eo);
    atomicAdd(&cnt[dv], 1);
}

__global__ __launch_bounds__(256) void scan1_k(const int* __restrict__ cnt, int* __restrict__ rowptr,
                                               int* __restrict__ bsum, int n) {
    __shared__ int ts[256];
    int tid = threadIdx.x;
    int base = blockIdx.x * 1024 + tid * 4;
    int v0 = (base + 0 < n) ? cnt[base + 0] : 0;
    int v1 = (base + 1 < n) ? cnt[base + 1] : 0;
    int v2 = (base + 2 < n) ? cnt[base + 2] : 0;
    int v3 = (base + 3 < n) ? cnt[base + 3] : 0;
    int e1 = v0, e2 = e1 + v1, e3 = e2 + v2, tot = e3 + v3;
    ts[tid] = tot;
    __syncthreads();
    for (int off = 1; off < 256; off <<= 1) {
        int x = (tid >= off) ? ts[tid - off] : 0;
        __syncthreads();
        ts[tid] += x;
        __syncthreads();
    }
    int excl = ts[tid] - tot;
    if (base + 0 < n) rowptr[base + 0] = excl;
    if (base + 1 < n) rowptr[base + 1] = excl + e1;
    if (base + 2 < n) rowptr[base + 2] = excl + e2;
    if (base + 3 < n) rowptr[base + 3] = excl + e3;
    if (tid == 255) bsum[blockIdx.x] = ts[255];
}

// 64-lane shfl exclusive scan (nb <= 64)
__global__ void scan2_k(int* __restrict__ bsum, int nb) {
    int t = threadIdx.x;
    int orig = (t < nb) ? bsum[t] : 0;
    int v = orig;
    for (int off = 1; off < 64; off <<= 1) {
        int u = __shfl_up(v, off);
        if (t >= off) v += u;
    }
    if (t < nb) bsum[t] = v - orig;
}

__global__ void scan3_k(int* __restrict__ rowptr, int* __restrict__ cursors,
                        const int* __restrict__ bsum, int n) {
    int gid = blockIdx.x * blockDim.x + threadIdx.x;
    if (gid >= n) return;
    int v = rowptr[gid] + bsum[gid >> 10];
    rowptr[gid] = v;
    cursors[gid] = v;
}

// scatter SRC node ids directly into csr_src (order fixed by later value-sort)
__global__ void scatter_k(const int* __restrict__ ei, int* __restrict__ cursors,
                          int* __restrict__ csr_src, int Eo, int Eext) {
    int e = blockIdx.x * blockDim.x + threadIdx.x;
    if (e >= Eext) return;
    int sv, dv;
    if (e < Eo) { sv = ei[e]; dv = ei[Eo + e]; }
    else        { sv = dv = e - Eo; }
    int idx = atomicAdd(&cursors[dv], 1);
    csr_src[idx] = sv;
}

// wave-group parallel rank-sort of src values within each node segment.
// 16 lanes per node; segment staged in LDS; rank = #{smaller} + #{equal before me}.
// Output = sorted multiset -> deterministic regardless of scatter order.
__global__ __launch_bounds__(256) void sortw_k(const int* __restrict__ rowptr, const int* __restrict__ cnt,
                                               int* __restrict__ csr_src, int n) {
    __shared__ int buf[16][128];
    int grp = threadIdx.x >> 4;         // 16 groups per block
    int sl  = threadIdx.x & 15;
    int node = blockIdx.x * 16 + grp;
    int ro = 0, deg = 0;
    if (node < n) { ro = rowptr[node]; deg = cnt[node]; }
    bool small = (deg <= 128);
    if (node < n && small) {
        for (int i = sl; i < deg; i += 16) buf[grp][i] = csr_src[ro + i];
    }
    __syncthreads();
    if (node < n) {
        if (small) {
            for (int i = sl; i < deg; i += 16) {
                int v = buf[grp][i];
                int r = 0;
                for (int j = 0; j < deg; j++) {
                    int u = buf[grp][j];
                    r += (u < v) || (u == v && j < i);
                }
                csr_src[ro + r] = v;
            }
        } else if (sl == 0) {
            for (int i = 1; i < deg; i++) {
                int key = csr_src[ro + i];
                int j = i - 1;
                while (j >= 0 && csr_src[ro + j] > key) { csr_src[ro + j + 1] = csr_src[ro + j]; j--; }
                csr_src[ro + j + 1] = key;
            }
        }
    }
}

// ---------------- MFMA GEMM (bf16 in, bf16 out) + fused scores + fused gmax ----------------
template<int K, int NOUT, int Hh>
__global__ __launch_bounds__(256) void gemm_mfma(const unsigned short* __restrict__ Xb,
                                                 const unsigned short* __restrict__ Wl,
                                                 const float* __restrict__ As,
                                                 const float* __restrict__ Ad,
                                                 unsigned short* __restrict__ Hb,
                                                 float* __restrict__ esrc,
                                                 float* __restrict__ edst,
                                                 unsigned int* __restrict__ gmaxb, int M) {
    constexpr int NT    = NOUT / 16;
    constexpr int TP    = (NT < 8) ? NT : 8;
    constexpr int NPASS = NT / TP;
    constexpr int NCH   = K / 8;
    constexpr int HPP   = (TP * 16) / 32;

    __shared__ unsigned short wlds[K * NOUT];
    {
        const uint4* src = (const uint4*)Wl;
        uint4* dst = (uint4*)wlds;
        for (int i = threadIdx.x; i < K * NOUT / 8; i += 256) dst[i] = src[i];
    }
    __syncthreads();

    const int lane = threadIdx.x & 63;
    const int wid  = threadIdx.x >> 6;
    const int l15  = lane & 15;
    const int g4   = lane >> 4;
    const int m0   = blockIdx.x * 128 + wid * 32;
    const int m_s[2] = { m0 + l15, m0 + 16 + l15 };
    const int mi[2]  = { min(m_s[0], M - 1), min(m_s[1], M - 1) };

    const bf16x8* xb8 = (const bf16x8*)Xb;
    const bf16x8* wl8 = (const bf16x8*)wlds;

    float gmx = 0.f;

    for (int pass = 0; pass < NPASS; ++pass) {
        f32x4 acc[TP][2];
#pragma unroll
        for (int tt = 0; tt < TP; ++tt)
#pragma unroll
            for (int s = 0; s < 2; ++s) acc[tt][s] = (f32x4)0.f;

        for (int ks = 0; ks < K / 32; ++ks) {
            int kc = ks * 4 + g4;
            bf16x8 a0 = xb8[(size_t)mi[0] * NCH + kc];
            bf16x8 a1 = xb8[(size_t)mi[1] * NCH + kc];
#pragma unroll
            for (int tt = 0; tt < TP; ++tt) {
                int nn = (pass * TP + tt) * 16 + l15;
                bf16x8 b = wl8[kc * NOUT + nn];
                acc[tt][0] = __builtin_amdgcn_mfma_f32_16x16x32_bf16(b, a0, acc[tt][0], 0, 0, 0);
                acc[tt][1] = __builtin_amdgcn_mfma_f32_16x16x32_bf16(b, a1, acc[tt][1], 0, 0, 0);
            }
        }

        float s1[2][HPP], s2[2][HPP];
#pragma unroll
        for (int s = 0; s < 2; ++s)
#pragma unroll
            for (int hh = 0; hh < HPP; ++hh) { s1[s][hh] = 0.f; s2[s][hh] = 0.f; }

#pragma unroll
        for (int tt = 0; tt < TP; ++tt) {
            int t  = pass * TP + tt;
            int ch = t * 16 + g4 * 4;
            float4 asv = *(const float4*)(As + ch);
            float4 adv = *(const float4*)(Ad + ch);
            int hh = tt >> 1;
#pragma unroll
            for (int s = 0; s < 2; ++s) {
                f32x4 a = acc[tt][s];
                s1[s][hh] += a[0] * asv.x + a[1] * asv.y + a[2] * asv.z + a[3] * asv.w;
                s2[s][hh] += a[0] * adv.x + a[1] * adv.y + a[2] * adv.z + a[3] * adv.w;
                int m = m_s[s];
                if (m < M) {
                    ushort4 o;
                    o.x = f2bf(a[0]); o.y = f2bf(a[1]); o.z = f2bf(a[2]); o.w = f2bf(a[3]);
                    *(ushort4*)(Hb + (size_t)m * NOUT + ch) = o;
                }
            }
        }
#pragma unroll
        for (int s = 0; s < 2; ++s) {
            int m = m_s[s];
#pragma unroll
            for (int hh = 0; hh < HPP; ++hh) {
                float p1 = s1[s][hh], p2 = s2[s][hh];
                p1 += __shfl_xor(p1, 16); p1 += __shfl_xor(p1, 32);
                p2 += __shfl_xor(p2, 16); p2 += __shfl_xor(p2, 32);
                gmx = fmaxf(gmx, fabsf(p1));
                if (g4 == 0 && m < M) {
                    int h = pass * HPP + hh;
                    esrc[m * Hh + h] = p1;
                    edst[m * Hh + h] = p2;
                }
            }
        }
    }

    gmx = fmaxf(gmx, __shfl_xor(gmx, 1));
    gmx = fmaxf(gmx, __shfl_xor(gmx, 2));
    gmx = fmaxf(gmx, __shfl_xor(gmx, 4));
    gmx = fmaxf(gmx, __shfl_xor(gmx, 8));
    if (lane == 0) atomicMax(gmaxb, __float_as_uint(gmx));
}

// ---------------- fused softmax(ub) + gather-aggregate (unroll-4, low VGPR) ----------------
__device__ inline void acc_bf8(float* acc, float a, uint4 p) {
    unsigned int u[4] = {p.x, p.y, p.z, p.w};
#pragma unroll
    for (int w = 0; w < 4; w++) {
        float lo = __uint_as_float(u[w] << 16);
        float hi = __uint_as_float(u[w] & 0xffff0000u);
        acc[2 * w + 0] += a * lo;
        acc[2 * w + 1] += a * hi;
    }
}

template<int HC, int Hh, bool PRED>
__global__ __launch_bounds__(256) void aggr_fused(const int* __restrict__ rowptr, const int* __restrict__ cnt,
                                                  const int* __restrict__ csr_src,
                                                  const float* __restrict__ esrc, const float* __restrict__ edst,
                                                  const unsigned int* __restrict__ gmaxb,
                                                  const unsigned short* __restrict__ Hb,
                                                  const float* __restrict__ bias,
                                                  unsigned short* __restrict__ OutB,
                                                  float* __restrict__ psrc, float* __restrict__ pdst,
                                                  const float* __restrict__ Wp, int n) {
    constexpr int TPN = HC / 8;
    constexpr int NPB = 256 / TPN;
    int node = blockIdx.x * NPB + threadIdx.x / TPN;
    if (node >= n) return;
    int t = threadIdx.x % TPN;
    int h = t >> 2;
    int sub = t & 3;
    int ro = rowptr[node], deg = cnt[node];
    float ed = edst[node * Hh + h];
    float g  = __uint_as_float(*gmaxb);
    float ub = g + ed; ub = (ub >= 0.f) ? ub : NEG_SLOPE * ub;   // >= max_j leaky(esrc[j]+ed)

    float s = 0.f;
    float acc[8];
#pragma unroll
    for (int c = 0; c < 8; c++) acc[c] = 0.f;

    int j = 0;
    for (; j + 4 <= deg; j += 4) {
        int s0 = csr_src[ro + j + 0], s1 = csr_src[ro + j + 1];
        int s2 = csr_src[ro + j + 2], s3 = csr_src[ro + j + 3];
        float v0 = esrc[s0 * Hh + h] + ed, v1 = esrc[s1 * Hh + h] + ed;
        float v2 = esrc[s2 * Hh + h] + ed, v3 = esrc[s3 * Hh + h] + ed;
        v0 = (v0 >= 0.f) ? v0 : NEG_SLOPE * v0;
        v1 = (v1 >= 0.f) ? v1 : NEG_SLOPE * v1;
        v2 = (v2 >= 0.f) ? v2 : NEG_SLOPE * v2;
        v3 = (v3 >= 0.f) ? v3 : NEG_SLOPE * v3;
        float a0 = __expf(v0 - ub), a1 = __expf(v1 - ub);
        float a2 = __expf(v2 - ub), a3 = __expf(v3 - ub);
        uint4 p0 = *(const uint4*)(Hb + (size_t)s0 * HC + 8 * t);
        uint4 p1 = *(const uint4*)(Hb + (size_t)s1 * HC + 8 * t);
        uint4 p2 = *(const uint4*)(Hb + (size_t)s2 * HC + 8 * t);
        uint4 p3 = *(const uint4*)(Hb + (size_t)s3 * HC + 8 * t);
        s += a0 + a1 + a2 + a3;
        acc_bf8(acc, a0, p0);
        acc_bf8(acc, a1, p1);
        acc_bf8(acc, a2, p2);
        acc_bf8(acc, a3, p3);
    }
    for (; j < deg; j++) {
        int s0 = csr_src[ro + j];
        float v0 = esrc[s0 * Hh + h] + ed;
        v0 = (v0 >= 0.f) ? v0 : NEG_SLOPE * v0;
        float a0 = __expf(v0 - ub);
        uint4 p0 = *(const uint4*)(Hb + (size_t)s0 * HC + 8 * t);
        s += a0;
        acc_bf8(acc, a0, p0);
    }

    float inv = 1.f / (s + 1e-16f);

    if (PRED) {
        float d1 = 0.f, d2 = 0.f;
#pragma unroll
        for (int c = 0; c < 8; c++) {
            float v = acc[c] * inv + bias[sub * 8 + c];
            v = v > 0.f ? v : 0.f;
            d1 += v * Wp[sub * 8 + c];
            d2 += v * Wp[32 + sub * 8 + c];
        }
        d1 += __shfl_xor(d1, 1); d1 += __shfl_xor(d1, 2);
        d2 += __shfl_xor(d2, 1); d2 += __shfl_xor(d2, 2);
        if (sub == 0) {
            psrc[node] = d1;
            pdst[node] = d2;
        }
    } else {
        uint4 o;
        unsigned int* op = (unsigned int*)&o;
#pragma unroll
        for (int w = 0; w < 4; w++) {
            float va = acc[2 * w + 0] * inv + bias[8 * t + 2 * w + 0];
            float vb = acc[2 * w + 1] * inv + bias[8 * t + 2 * w + 1];
            va = va > 0.f ? va : 0.f;
            vb = vb > 0.f ? vb : 0.f;
            op[w] = (unsigned int)f2bf(va) | ((unsigned int)f2bf(vb) << 16);
        }
        *(uint4*)(OutB + (size_t)node * HC + 8 * t) = o;
    }
}

// ---------------- rank-1 edge predictor ----------------
__global__ void predict2_k(const int* __restrict__ ei, const float* __restrict__ psrc,
                           const float* __restrict__ pdst, const float* __restrict__ bp,
                           float* __restrict__ out, int Eo) {
    int e = blockIdx.x * blockDim.x + threadIdx.x;
    if (e >= Eo) return;
    float acc = psrc[ei[e]] + pdst[ei[Eo + e]] + bp[0];
    float sg = 1.f / (1.f + __expf(-acc));
    out[e] = sg * 4.f + 1.f;
}

extern "C" void kernel_launch(void* const* d_in, const int* in_sizes, int n_in,
                              void* d_out, int out_size, void* d_ws, size_t ws_size,
                              hipStream_t stream) {
    const float* x   = (const float*)d_in[0];
    const int*   ei  = (const int*)  d_in[1];
    const float* W1  = (const float*)d_in[2];
    const float* as1 = (const float*)d_in[3];
    const float* ad1 = (const float*)d_in[4];
    const float* b1  = (const float*)d_in[5];
    const float* W2  = (const float*)d_in[6];
    const float* as2 = (const float*)d_in[7];
    const float* ad2 = (const float*)d_in[8];
    const float* b2  = (const float*)d_in[9];
    const float* W3  = (const float*)d_in[10];
    const float* as3 = (const float*)d_in[11];
    const float* ad3 = (const float*)d_in[12];
    const float* b3  = (const float*)d_in[13];
    const float* Wp  = (const float*)d_in[14];
    const float* bp  = (const float*)d_in[15];
    float* outp = (float*)d_out;

    const int n    = in_sizes[0] / 128;   // 50000
    const int Eo   = in_sizes[1] / 2;     // 800000
    const int Eext = Eo + n;              // 850000

    char* base = (char*)d_ws;
    unsigned short* hAb = (unsigned short*)base;   base += (size_t)n * 256 * 2;
    unsigned short* hBb = (unsigned short*)base;   base += (size_t)n * 256 * 2;
    unsigned short* Xb  = (unsigned short*)base;   base += (size_t)n * 128 * 2;
    unsigned short* Wl1 = (unsigned short*)base;   base += (size_t)128 * 256 * 2;
    unsigned short* Wl2 = (unsigned short*)base;   base += (size_t)256 * 128 * 2;
    unsigned short* Wl3 = (unsigned short*)base;   base += (size_t)128 * 32 * 2;
    float* esrc   = (float*)base;                  base += (size_t)n * 8 * 4;
    float* edst   = (float*)base;                  base += (size_t)n * 8 * 4;
    float* psrc   = (float*)base;                  base += (size_t)n * 4;
    float* pdst   = (float*)base;                  base += (size_t)n * 4;
    int* cnt      = (int*)base;                    base += (size_t)n * 4;
    unsigned int* gmaxb = (unsigned int*)base;     base += 16;
    int* rowptr   = (int*)base;                    base += (size_t)n * 4;
    int* cursors  = (int*)base;                    base += (size_t)n * 4;
    int* csr_src  = (int*)base;                    base += (size_t)Eext * 4;
    int* bsum     = (int*)base;

    const int TB = 256;
    auto nb = [](int tot, int tb) { return (tot + tb - 1) / tb; };

    // ---------------- prep (x/W conversions + zero cnt/gmax) ----------------
    int nx4 = n * 128 / 4, ncnt4 = n / 4;
    int prep_total = nx4 + 4096 + 4096 + 512 + ncnt4 + 1;
    prep_all_k<<<nb(prep_total, TB), TB, 0, stream>>>(x, Xb, W1, Wl1, W2, Wl2, W3, Wl3,
                                                      cnt, gmaxb, nx4, ncnt4);

    // ---------------- CSR build (dst-sorted, value-sorted src) ----------------
    hist_k<<<nb(Eext, TB), TB, 0, stream>>>(ei, cnt, Eo, Eext);
    int nChunks = (n + 1023) / 1024;
    scan1_k<<<nChunks, 256, 0, stream>>>(cnt, rowptr, bsum, n);
    scan2_k<<<1, 64, 0, stream>>>(bsum, nChunks);
    scan3_k<<<nb(n, TB), TB, 0, stream>>>(rowptr, cursors, bsum, n);
    scatter_k<<<nb(Eext, TB), TB, 0, stream>>>(ei, cursors, csr_src, Eo, Eext);
    sortw_k<<<nb(n, 16), 256, 0, stream>>>(rowptr, cnt, csr_src, n);

    // ---------------- Layer 1: K=128, H=8, HC=256 ----------------
    gemm_mfma<128, 256, 8><<<nb(n, 128), 256, 0, stream>>>(Xb, Wl1, as1, ad1, hAb, esrc, edst, gmaxb + 0, n);
    aggr_fused<256, 8, false><<<nb(n * 32, TB), TB, 0, stream>>>(rowptr, cnt, csr_src, esrc, edst, gmaxb + 0,
                                                                 hAb, b1, hBb, nullptr, nullptr, nullptr, n);

    // ---------------- Layer 2: K=256, H=4, HC=128 ----------------
    gemm_mfma<256, 128, 4><<<nb(n, 128), 256, 0, stream>>>(hBb, Wl2, as2, ad2, hAb, esrc, edst, gmaxb + 1, n);
    aggr_fused<128, 4, false><<<nb(n * 16, TB), TB, 0, stream>>>(rowptr, cnt, csr_src, esrc, edst, gmaxb + 1,
                                                                 hAb, b2, hBb, nullptr, nullptr, nullptr, n);

    // ---------------- Layer 3: K=128, H=1, HC=32 (fused rank-1 predictor dots) ----------------
    gemm_mfma<128, 32, 1><<<nb(n, 128), 256, 0, stream>>>(hBb, Wl3, as3, ad3, hAb, esrc, edst, gmaxb + 2, n);
    aggr_fused<32, 1, true><<<nb(n * 4, TB), TB, 0, stream>>>(rowptr, cnt, csr_src, esrc, edst, gmaxb + 2,
                                                              hAb, b3, nullptr, psrc, pdst, Wp, n);

    // ---------------- predictor ----------------
    predict2_k<<<nb(Eo, TB), TB, 0, stream>>>(ei, psrc, pdst, bp, outp, Eo);
}